// Round 7
// baseline (348.988 us; speedup 1.0000x reference)
//
#include <hip/hip_runtime.h>
#include <stdint.h>

#define NN 50000
#define NE 800000
#define NG 512
#define H  128
#define NBK 196      // ceil(NN/256) node buckets
#define EPB 3125     // edges per partition block (NE/256)

typedef __attribute__((ext_vector_type(8))) short short8;
typedef __attribute__((ext_vector_type(16))) float f32x16;
typedef __attribute__((ext_vector_type(2))) float float2v;

union U4S8 { uint4 u; short8 s; };

__device__ __forceinline__ float softplusf(float x){
    return fmaxf(x, 0.f) + log1pf(expf(-fabsf(x)));
}

__device__ __forceinline__ unsigned rne_bf16_hi(float x){
    unsigned u = __float_as_uint(x);
    unsigned r = u + 0x7fffu + ((u >> 16) & 1u);
    return r & 0xffff0000u;
}

__device__ __forceinline__ void split_pack(float x0, float x1, unsigned &hi, unsigned &lo){
    unsigned h0 = rne_bf16_hi(x0), h1 = rne_bf16_hi(x1);
    hi = (h0 >> 16) | h1;
    float l0 = x0 - __uint_as_float(h0);
    float l1 = x1 - __uint_as_float(h1);
    unsigned g0 = rne_bf16_hi(l0), g1 = rne_bf16_hi(l1);
    lo = (g0 >> 16) | g1;
}

// ---------------- sentinel writer ----------------
__global__ void k_sentinel(float* out, float val){
    int i = blockIdx.x*256 + threadIdx.x;
    if (i < 6*NG) out[i] = val;
}

// ================ K1: merged {W_comb split | GIN W split | edge hist} ================
__global__ __launch_bounds__(256) void k_pre(
    const float* __restrict__ Wc, uint4* __restrict__ wcf,
    const float* __restrict__ gW1, const float* __restrict__ gW2, uint4* __restrict__ wf,
    const int* __restrict__ ei, int* __restrict__ cnt)
{
    __shared__ int hist[256];
    const int bx = blockIdx.x, t = threadIdx.x;
    if (bx < 16){
        int bid = bx*4 + (t >> 6), lane = t & 63;
        int ntg = bid >> 4, ks = bid & 15;
        int n  = ntg*32 + (lane & 31);
        int kb = ks*16 + (lane >> 5)*8;
        unsigned hi[4], lo[4];
#pragma unroll
        for (int d=0; d<4; d++){
            float x0 = Wc[(size_t)(kb + 2*d    )*H + n];
            float x1 = Wc[(size_t)(kb + 2*d + 1)*H + n];
            split_pack(x0, x1, hi[d], lo[d]);
        }
        wcf[((0*4 + ntg)*16 + ks)*64 + lane] = make_uint4(hi[0],hi[1],hi[2],hi[3]);
        wcf[((1*4 + ntg)*16 + ks)*64 + lane] = make_uint4(lo[0],lo[1],lo[2],lo[3]);
    } else if (bx < 80){
        int bid = (bx-16)*4 + (t >> 6), lane = t & 63;
        int mat = bid >> 5, ntg = (bid >> 3) & 3, ks = bid & 7;
        int l = mat >> 1;
        const float* W = (mat & 1) ? (gW2 + (size_t)l*H*H) : (gW1 + (size_t)l*H*H);
        int n  = ntg*32 + (lane & 31);
        int kb = ks*16 + (lane >> 5)*8;
        unsigned hi[4], lo[4];
#pragma unroll
        for (int d=0; d<4; d++){
            float x0 = W[(size_t)(kb + 2*d    )*H + n];
            float x1 = W[(size_t)(kb + 2*d + 1)*H + n];
            split_pack(x0, x1, hi[d], lo[d]);
        }
        int bh = ((mat*2 + 0)*4 + ntg)*8 + ks;
        int bl = ((mat*2 + 1)*4 + ntg)*8 + ks;
        wf[bh*64 + lane] = make_uint4(hi[0],hi[1],hi[2],hi[3]);
        wf[bl*64 + lane] = make_uint4(lo[0],lo[1],lo[2],lo[3]);
    } else {
        int blk = bx - 80;
        hist[t] = 0;
        __syncthreads();
        int e0 = blk*EPB, e1 = min(e0+EPB, NE);
        for (int e = e0+t; e < e1; e += 256){
            int d = ei[NE+e];
            if ((unsigned)d < NN) atomicAdd(&hist[d>>8], 1);
        }
        __syncthreads();
        if (t < NBK) cnt[t*256 + blk] = hist[t];
    }
}

// ================ K2: merged {initial embedding MFMA | bucket totals} ================
// blocks 0..781 : embed role (writes fp8 xb);  blocks 782..977 : btot role
__global__ __launch_bounds__(256) void k_embed_btot(const int* __restrict__ z,
    const float* __restrict__ pos, const float* __restrict__ emb,
    const float* __restrict__ Wp, const float* __restrict__ bp,
    const float* __restrict__ bc, const uint4* __restrict__ wcf,
    unsigned* __restrict__ xbu,
    const int* __restrict__ cnt, int* __restrict__ tot)
{
    __shared__ unsigned short AhiF[2*8*64*8];
    __shared__ unsigned short AloF[2*8*64*8];
    const int t = threadIdx.x;
    if (blockIdx.x >= 782){
        int* s = (int*)AhiF;
        int k = blockIdx.x - 782;
        s[t] = cnt[k*256 + t];
        __syncthreads();
        for (int sd=128; sd>0; sd>>=1){
            if (t < sd) s[t] += s[t+sd];
            __syncthreads();
        }
        if (t == 0) tot[k] = s[0];
        return;
    }
    const int lane = t & 63, w = t >> 6;
    const int rt = w & 1, cp = w >> 1;
    const int mb = blockIdx.x * 64;
    const int c31 = lane & 31;
    const int q = lane >> 5;

    const int r = t >> 2, c4 = t & 3;
    const int gr = mb + r;
    const int gre = (gr < NN) ? gr : (NN-1);
    const int zr = z[gre];
    const float p0 = pos[gre*3+0], p1 = pos[gre*3+1], p2 = pos[gre*3+2];
    const int rt_s = r >> 5, r31s = r & 31;

    f32x16 acc0, acc1;
#pragma unroll
    for (int i=0;i<16;i++){ acc0[i]=0.f; acc1[i]=0.f; }

#pragma unroll
    for (int kh2=0; kh2<2; kh2++){
        if (kh2) __syncthreads();
#pragma unroll
        for (int i=0;i<8;i++){
            int cl = c4*4 + i*16;
            float4 v;
            if (kh2 == 0){
                v = *(const float4*)(emb + (size_t)zr*H + cl);
            } else {
                float4 w0 = *(const float4*)(Wp + cl);
                float4 w1 = *(const float4*)(Wp + H + cl);
                float4 w2 = *(const float4*)(Wp + 2*H + cl);
                float4 bb = *(const float4*)(bp + cl);
                v.x = p0*w0.x + p1*w1.x + p2*w2.x + bb.x;
                v.y = p0*w0.y + p1*w1.y + p2*w2.y + bb.y;
                v.z = p0*w0.z + p1*w1.z + p2*w2.z + bb.z;
                v.w = p0*w0.w + p1*w1.w + p2*w2.w + bb.w;
            }
            unsigned h0,l0,h1,l1;
            split_pack(v.x, v.y, h0, l0);
            split_pack(v.z, v.w, h1, l1);
            int idx = ((rt_s*8 + (cl>>4))*64 + ((cl>>3)&1)*32 + r31s)*8 + (cl & 7);
            *(uint2*)&AhiF[idx] = make_uint2(h0, h1);
            *(uint2*)&AloF[idx] = make_uint2(l0, l1);
        }
        __syncthreads();
#pragma unroll
        for (int ks=0; ks<8; ks++){
            int ksg = kh2*8 + ks;
            U4S8 ah, al, bh0, bl0, bh1, bl1;
            ah.u  = *(const uint4*)&AhiF[((rt*8+ks)*64 + lane)*8];
            al.u  = *(const uint4*)&AloF[((rt*8+ks)*64 + lane)*8];
            bh0.u = wcf[((0*4 + 2*cp+0)*16 + ksg)*64 + lane];
            bl0.u = wcf[((1*4 + 2*cp+0)*16 + ksg)*64 + lane];
            bh1.u = wcf[((0*4 + 2*cp+1)*16 + ksg)*64 + lane];
            bl1.u = wcf[((1*4 + 2*cp+1)*16 + ksg)*64 + lane];
            acc0 = __builtin_amdgcn_mfma_f32_32x32x16_bf16(ah.s, bh0.s, acc0, 0,0,0);
            acc0 = __builtin_amdgcn_mfma_f32_32x32x16_bf16(ah.s, bl0.s, acc0, 0,0,0);
            acc0 = __builtin_amdgcn_mfma_f32_32x32x16_bf16(al.s, bh0.s, acc0, 0,0,0);
            acc1 = __builtin_amdgcn_mfma_f32_32x32x16_bf16(ah.s, bh1.s, acc1, 0,0,0);
            acc1 = __builtin_amdgcn_mfma_f32_32x32x16_bf16(ah.s, bl1.s, acc1, 0,0,0);
            acc1 = __builtin_amdgcn_mfma_f32_32x32x16_bf16(al.s, bh1.s, acc1, 0,0,0);
        }
    }

    const float bva = bc[64*cp + c31], bvb = bc[64*cp + 32 + c31];
#pragma unroll
    for (int reg=0; reg<16; reg++){
        int row = 32*rt + (reg & 3) + 8*(reg >> 2) + 4*q;
        int mm = mb + row;
        if (mm < NN){
            float v0 = fmaxf(acc0[reg] + bva, 0.f);   // col 64cp + c31
            float v1 = fmaxf(acc1[reg] + bvb, 0.f);   // col 64cp + 32 + c31
            float pa = __shfl_xor(v0, 1);
            float pb = __shfl_xor(v1, 1);
            unsigned q0 = (unsigned)__builtin_amdgcn_cvt_pk_fp8_f32(v0, pa, 0, false) & 0xffffu;
            unsigned q1 = (unsigned)__builtin_amdgcn_cvt_pk_fp8_f32(v1, pb, 0, false) & 0xffffu;
            unsigned r0 = (unsigned)__shfl_xor((int)q0, 2);
            unsigned r1 = (unsigned)__shfl_xor((int)q1, 2);
            if (!(lane & 3)){
                xbu[(size_t)mm*32 + 16*cp      + (c31>>2)] = q0 | (r0 << 16);
                xbu[(size_t)mm*32 + 16*cp + 8  + (c31>>2)] = q1 | (r1 << 16);
            }
        }
    }
}

// ================ K3: soff with inline scan-of-totals ================
__global__ __launch_bounds__(256) void k_soff2(const int* __restrict__ cnt,
    const int* __restrict__ tot, int* __restrict__ soff, int* __restrict__ bb)
{
    __shared__ int P[256], sc[256];
    int k = blockIdx.x, t = threadIdx.x;
    int tv = (t < NBK) ? tot[t] : 0;
    P[t] = tv;
    for (int off=1; off<256; off<<=1){
        __syncthreads();
        int a = (t >= off) ? P[t-off] : 0;
        __syncthreads();
        P[t] += a;
    }
    __syncthreads();
    int bbk = (k == 0) ? 0 : P[k-1];
    if (k == 0){
        if (t == 0) bb[0] = 0;
        if (t < NBK) bb[t+1] = P[t];
    }
    int v = cnt[k*256 + t];
    sc[t] = v;
    for (int off=1; off<256; off<<=1){
        __syncthreads();
        int a = (t >= off) ? sc[t-off] : 0;
        __syncthreads();
        sc[t] += a;
    }
    __syncthreads();
    soff[k*256 + t] = bbk + sc[t] - v;
}

// ---------------- FUSED GIN layer v7: single-pass gather, 8 lanes x 16B per row ----------------
__global__ __launch_bounds__(256) void k_gin_fused(
    const unsigned* __restrict__ xbin,
    const int* __restrict__ iptr, const int* __restrict__ esrc,
    const float* __restrict__ b1, const float* __restrict__ b2,
    const uint4* __restrict__ wf,
    float* __restrict__ xout, unsigned* __restrict__ xbout,
    int l, int relu2, int wx, int wxb)
{
    __shared__ unsigned short AhiF[8*64*8];   // 8 KB
    __shared__ unsigned short AloF[8*64*8];   // 8 KB
    __shared__ int eS[1024];                  // 4 KB staged edge indices
    const int t = threadIdx.x, lane = t & 63, w = t >> 6;
    const int mb = blockIdx.x * 32;
    const int c31 = lane & 31;
    const int q = lane >> 5;
    const int c8 = lane & 7;        // 16B chunk within row (16 cols)
    const int r8 = lane >> 3;       // row within wave group (0..7)
    const int m  = w*8 + r8;        // tile row 0..31

    const uint4* __restrict__ xb4 = (const uint4*)xbin;   // row stride 8 uint4 (128 B)

    // ---- stage this block's contiguous edge-index range into LDS ----
    const int eTop = (mb + 32 < NN) ? (mb + 32) : NN;
    int e0b = iptr[mb];
    int e1b = iptr[eTop];
    e0b = max(0, min(e0b, NE));
    e1b = max(e0b, min(e1b, NE));
    const int ecnt = e1b - e0b;
    for (int i = t; i < ecnt && i < 1024; i += 256) eS[i] = esrc[e0b + i];
    __syncthreads();
    const int eCap = e0b + 1024;

#define ACC16(U) { float2v _f; \
    _f = __builtin_amdgcn_cvt_pk_f32_fp8((int)(U).x, false); a0  += _f.x; a1  += _f.y; \
    _f = __builtin_amdgcn_cvt_pk_f32_fp8((int)(U).x, true ); a2  += _f.x; a3  += _f.y; \
    _f = __builtin_amdgcn_cvt_pk_f32_fp8((int)(U).y, false); a4  += _f.x; a5  += _f.y; \
    _f = __builtin_amdgcn_cvt_pk_f32_fp8((int)(U).y, true ); a6  += _f.x; a7  += _f.y; \
    _f = __builtin_amdgcn_cvt_pk_f32_fp8((int)(U).z, false); a8  += _f.x; a9  += _f.y; \
    _f = __builtin_amdgcn_cvt_pk_f32_fp8((int)(U).z, true ); a10 += _f.x; a11 += _f.y; \
    _f = __builtin_amdgcn_cvt_pk_f32_fp8((int)(U).w, false); a12 += _f.x; a13 += _f.y; \
    _f = __builtin_amdgcn_cvt_pk_f32_fp8((int)(U).w, true ); a14 += _f.x; a15 += _f.y; }

#define GLOOP(IX) { \
    for (; j+8 <= e; j += 8){ \
        int i0=IX(j+0), i1=IX(j+1), i2=IX(j+2), i3=IX(j+3); \
        int i4=IX(j+4), i5=IX(j+5), i6=IX(j+6), i7=IX(j+7); \
        uint4 u0 = xb4[(unsigned)i0*8u + c8]; \
        uint4 u1 = xb4[(unsigned)i1*8u + c8]; \
        uint4 u2 = xb4[(unsigned)i2*8u + c8]; \
        uint4 u3 = xb4[(unsigned)i3*8u + c8]; \
        uint4 u4 = xb4[(unsigned)i4*8u + c8]; \
        uint4 u5 = xb4[(unsigned)i5*8u + c8]; \
        uint4 u6 = xb4[(unsigned)i6*8u + c8]; \
        uint4 u7 = xb4[(unsigned)i7*8u + c8]; \
        ACC16(u0); ACC16(u1); ACC16(u2); ACC16(u3); \
        ACC16(u4); ACC16(u5); ACC16(u6); ACC16(u7); \
    } \
    for (; j+2 <= e; j += 2){ \
        int i0=IX(j+0), i1=IX(j+1); \
        uint4 u0 = xb4[(unsigned)i0*8u + c8]; \
        uint4 u1 = xb4[(unsigned)i1*8u + c8]; \
        ACC16(u0); ACC16(u1); \
    } \
    if (j < e){ \
        int i0=IX(j); \
        uint4 u0 = xb4[(unsigned)i0*8u + c8]; \
        ACC16(u0); \
    } }

#define EIX_L(J) eS[(J) - e0b]
#define EIX_G(J) esrc[(J)]

    {
        const int mm = mb + m;
        const int mme = (mm < NN) ? mm : (NN-1);
        int s = iptr[mme], e = iptr[mme+1];
        s = max(0, min(s, NE));
        e = max(s, min(e, NE));
        float a0=0.f,a1=0.f,a2=0.f,a3=0.f,a4=0.f,a5=0.f,a6=0.f,a7=0.f;
        float a8=0.f,a9=0.f,a10=0.f,a11=0.f,a12=0.f,a13=0.f,a14=0.f,a15=0.f;
        // self term
        {
            uint4 su = xb4[(size_t)mme*8 + c8];
            ACC16(su);
        }
        int j = s;
        if (s >= e0b && e <= eCap){
            GLOOP(EIX_L);
        } else {
            GLOOP(EIX_G);
        }
        // cols c8*16 + 0..7  -> entry (ks=c8, qw=0);  +8..15 -> (ks=c8, qw=1)
        unsigned h0,h1,h2,h3,l0,l1,l2,l3;
        split_pack(a0,a1,h0,l0);  split_pack(a2,a3,h1,l1);
        split_pack(a4,a5,h2,l2);  split_pack(a6,a7,h3,l3);
        int idxA = (c8*64 + (m ^ c8))*8;
        *(uint4*)&AhiF[idxA] = make_uint4(h0,h1,h2,h3);
        *(uint4*)&AloF[idxA] = make_uint4(l0,l1,l2,l3);
        split_pack(a8,a9,h0,l0);   split_pack(a10,a11,h1,l1);
        split_pack(a12,a13,h2,l2); split_pack(a14,a15,h3,l3);
        int idxB = (c8*64 + 32 + (m ^ c8))*8;
        *(uint4*)&AhiF[idxB] = make_uint4(h0,h1,h2,h3);
        *(uint4*)&AloF[idxB] = make_uint4(l0,l1,l2,l3);
    }
#undef EIX_G
#undef EIX_L
#undef GLOOP
#undef ACC16
    __syncthreads();

    const float bv1 = b1[w*32 + c31];
    const float bv2 = b2[w*32 + c31];
    const int mat1 = l*2, mat2 = l*2 + 1;

    f32x16 acc;
#pragma unroll
    for (int i=0;i<16;i++) acc[i] = 0.f;

    // ---- phase 1: T = relu(h@W1 + b1) ----
#pragma unroll
    for (int ks=0; ks<8; ks++){
        U4S8 ah, al, bh, bl;
        ah.u = *(const uint4*)&AhiF[(ks*64 + q*32 + (c31 ^ ks))*8];
        al.u = *(const uint4*)&AloF[(ks*64 + q*32 + (c31 ^ ks))*8];
        bh.u = wf[(((mat1*2+0)*4 + w)*8 + ks)*64 + lane];
        bl.u = wf[(((mat1*2+1)*4 + w)*8 + ks)*64 + lane];
        acc = __builtin_amdgcn_mfma_f32_32x32x16_bf16(ah.s, bh.s, acc, 0,0,0);
        acc = __builtin_amdgcn_mfma_f32_32x32x16_bf16(ah.s, bl.s, acc, 0,0,0);
        acc = __builtin_amdgcn_mfma_f32_32x32x16_bf16(al.s, bh.s, acc, 0,0,0);
    }

    // ---- T -> LDS frag-order (bf16 hi/lo), swizzled ----
    __syncthreads();
    {
        int k   = w*32 + c31;
        int kst = k >> 4, qt = (k >> 3) & 1, jj = k & 7;
#pragma unroll
        for (int reg=0; reg<16; reg++){
            int row = (reg & 3) + 8*(reg >> 2) + 4*q;
            float v = fmaxf(acc[reg] + bv1, 0.f);
            int idx = (kst*64 + qt*32 + (row ^ kst))*8 + jj;
            unsigned hb = rne_bf16_hi(v);
            AhiF[idx] = (unsigned short)(hb >> 16);
            AloF[idx] = (unsigned short)(rne_bf16_hi(v - __uint_as_float(hb)) >> 16);
        }
    }
    __syncthreads();

    // ---- phase 2: Y = T@W2 + b2 ----
#pragma unroll
    for (int i=0;i<16;i++) acc[i] = 0.f;
#pragma unroll
    for (int ks=0; ks<8; ks++){
        U4S8 ah, al, bh, bl;
        ah.u = *(const uint4*)&AhiF[(ks*64 + q*32 + (c31 ^ ks))*8];
        al.u = *(const uint4*)&AloF[(ks*64 + q*32 + (c31 ^ ks))*8];
        bh.u = wf[(((mat2*2+0)*4 + w)*8 + ks)*64 + lane];
        bl.u = wf[(((mat2*2+1)*4 + w)*8 + ks)*64 + lane];
        acc = __builtin_amdgcn_mfma_f32_32x32x16_bf16(ah.s, bh.s, acc, 0,0,0);
        acc = __builtin_amdgcn_mfma_f32_32x32x16_bf16(ah.s, bl.s, acc, 0,0,0);
        acc = __builtin_amdgcn_mfma_f32_32x32x16_bf16(al.s, bh.s, acc, 0,0,0);
    }

    // ---- epilogue: conditional fp32 / fp8 outputs ----
#pragma unroll
    for (int reg=0; reg<16; reg++){
        int row = (reg & 3) + 8*(reg >> 2) + 4*q;
        int mm = mb + row;
        if (mm < NN){
            float v = acc[reg] + bv2;     // col w*32 + c31
            if (relu2) v = fmaxf(v, 0.f);
            if (wx) xout[(size_t)mm*H + w*32 + c31] = v;
            if (wxb){
                float p1 = __shfl_xor(v, 1);
                unsigned qq = (unsigned)__builtin_amdgcn_cvt_pk_fp8_f32(v, p1, 0, false) & 0xffffu;
                unsigned rr = (unsigned)__shfl_xor((int)qq, 2);
                if (!(lane & 3)){
                    xbout[(size_t)mm*32 + w*8 + (c31>>2)] = qq | (rr << 16);
                }
            }
        }
    }
}

// ================ CSR partition kernels ================
// k_part v2.1: histogram from cnt[] (computed in k_pre) — GUARDED for t >= NBK
// (v2 read uninitialized cnt for t in [196,255] -> corrupted scatter; round-6 fail)
__global__ __launch_bounds__(256) void k_part(const int* __restrict__ ei,
    const int* __restrict__ cnt, const int* __restrict__ soff, unsigned* __restrict__ tmp)
{
    __shared__ unsigned edgeL[EPB];
    __shared__ int sc[256], startv[256], curv[256];
    __shared__ int tots;
    int blk = blockIdx.x, t = threadIdx.x;
    int v = (t < NBK) ? cnt[t*256 + blk] : 0;
    sc[t] = v;
    for (int off=1; off<256; off<<=1){
        __syncthreads();
        int tv = (t >= off) ? sc[t-off] : 0;
        __syncthreads();
        sc[t] += tv;
    }
    __syncthreads();
    startv[t] = sc[t] - v;
    curv[t]   = sc[t] - v;
    if (t == 255) tots = sc[255];
    __syncthreads();
    int e0 = blk*EPB, e1 = min(e0+EPB, NE);
    for (int e = e0+t; e < e1; e += 256){
        int d = ei[NE+e];
        if ((unsigned)d < NN){
            unsigned u = (unsigned)ei[e] | ((unsigned)d << 16);
            int p = atomicAdd(&curv[d>>8], 1);
            edgeL[p] = u;
        }
    }
    __syncthreads();
    int nTot = tots;
    for (int i = t; i < nTot; i += 256){
        unsigned u = edgeL[i];
        int b = u >> 24;
        int g = soff[b*256 + blk] + (i - startv[b]);
        tmp[g] = u;
    }
}

__global__ __launch_bounds__(256) void k_final(const int* __restrict__ bb,
    const unsigned* __restrict__ tmp, int* __restrict__ esrc, int* __restrict__ iptr)
{
    __shared__ int cntN[256], sc[256], curN[256];
    int k = blockIdx.x, t = threadIdx.x;
    int n0 = k*256;
    int nn = min(256, NN - n0);
    int base = bb[k], end = bb[k+1];
    cntN[t] = 0;
    __syncthreads();
    for (int i = base+t; i < end; i += 256){
        int d = (int)(tmp[i] >> 16) - n0;
        if ((unsigned)d < 256u) atomicAdd(&cntN[d], 1);
    }
    __syncthreads();
    int v = cntN[t];
    sc[t] = v;
    for (int off=1; off<256; off<<=1){
        __syncthreads();
        int tv = (t >= off) ? sc[t-off] : 0;
        __syncthreads();
        sc[t] += tv;
    }
    __syncthreads();
    int excl = sc[t] - v;
    curN[t] = excl;
    if (t < nn) iptr[n0 + t] = base + excl;
    if (k == NBK-1 && t == 0) iptr[NN] = end;
    __syncthreads();
    for (int i = base+t; i < end; i += 256){
        unsigned u = tmp[i];
        int d = (int)(u >> 16) - n0;
        if ((unsigned)d < 256u){
            int p = atomicAdd(&curN[d], 1);
            esrc[base + p] = (int)(u & 0xffffu);
        }
    }
}

// ================ K6: fused pool + 4 heads + evidential epilogue (per graph) ================
__global__ __launch_bounds__(256) void k_phe(const float* __restrict__ x,
    const int* __restrict__ batch,
    const float* __restrict__ W1, const float* __restrict__ b1,
    const float* __restrict__ W2, const float* __restrict__ b2,
    float* __restrict__ out)
{
    __shared__ float aggL[128];
    __shared__ float redL[256];
    __shared__ float okL[4];
    int g = blockIdx.x, t = threadIdx.x;
    int c = t & 127, half = t >> 7;
    int lo=0, hi=NN;
    while (lo<hi){ int mid=(lo+hi)>>1; if (batch[mid] < g) lo=mid+1; else hi=mid; }
    int s0 = lo;
    hi = NN;
    while (lo<hi){ int mid=(lo+hi)>>1; if (batch[mid] < g+1) lo=mid+1; else hi=mid; }
    int e0 = lo;
    int n  = e0 - s0;
    int sh = s0 + (half ? (n>>1) : 0);
    int eh = half ? e0 : (s0 + (n>>1));
    float a0=0.f, a1=0.f, a2=0.f, a3=0.f;
    int i = sh;
    for (; i+4 <= eh; i += 4){
        a0 += x[(size_t)(i+0)*H + c];
        a1 += x[(size_t)(i+1)*H + c];
        a2 += x[(size_t)(i+2)*H + c];
        a3 += x[(size_t)(i+3)*H + c];
    }
    for (; i < eh; i++) a0 += x[(size_t)i*H + c];
    float v = (a0+a1) + (a2+a3);
    if (half) redL[c] = v;
    __syncthreads();
    if (!half) aggL[c] = v + redL[c];
    __syncthreads();
    for (int kk = half; kk < 4; kk += 2){
        float acc = b1[kk*H + c];
        const float* wp = W1 + (size_t)kk*H*H + c;
#pragma unroll 8
        for (int qq=0; qq<H; qq++) acc += aggL[qq] * wp[(size_t)qq*H];
        redL[half*128 + c] = fmaxf(acc, 0.f) * W2[kk*H + c];
        __syncthreads();
        for (int sd=64; sd>0; sd>>=1){
            if (c < sd) redL[half*128 + c] += redL[half*128 + c + sd];
            __syncthreads();
        }
        if (c == 0) okL[kk] = redL[half*128];
        __syncthreads();
    }
    if (t == 0){
        float o0 = okL[0] + b2[0];
        float o1 = okL[1] + b2[1];
        float o2 = okL[2] + b2[2];
        float o3 = okL[3] + b2[3];
        float alpha = fmaxf(softplusf(o0) + 1.f, 1.f + 1e-4f);
        float beta  = softplusf(o1);
        float nu    = softplusf(o2);
        float am1   = alpha - 1.f;
        out[0*NG+g] = o3;
        out[1*NG+g] = beta / am1;
        out[2*NG+g] = beta / (am1 * nu);
        out[3*NG+g] = nu;
        out[4*NG+g] = alpha;
        out[5*NG+g] = beta;
    }
}

extern "C" void kernel_launch(void* const* d_in, const int* in_sizes, int n_in,
                              void* d_out, int out_size, void* d_ws, size_t ws_size,
                              hipStream_t stream)
{
    const int*   z     = (const int*)d_in[0];
    const float* pos   = (const float*)d_in[1];
    const int*   batch = (const int*)d_in[2];
    const int*   eidx  = (const int*)d_in[3];
    const float* emb   = (const float*)d_in[4];
    const float* Wp    = (const float*)d_in[5];
    const float* bp    = (const float*)d_in[6];
    const float* Wc    = (const float*)d_in[7];
    const float* bc    = (const float*)d_in[8];
    const float* gW1   = (const float*)d_in[9];
    const float* gb1   = (const float*)d_in[10];
    const float* gW2   = (const float*)d_in[11];
    const float* gb2   = (const float*)d_in[12];
    const float* hW1   = (const float*)d_in[13];
    const float* hb1   = (const float*)d_in[14];
    const float* hW2   = (const float*)d_in[15];
    const float* hb2   = (const float*)d_in[16];
    float* out = (float*)d_out;

    bool ok_sizes = (n_in == 17)
        && in_sizes[0] == NN && in_sizes[1] == NN*3 && in_sizes[2] == NN
        && in_sizes[3] == 2*NE && in_sizes[4] == 100*H
        && in_sizes[7] == 2*H*H && in_sizes[9] == 4*H*H
        && in_sizes[13] == 4*H*H && in_sizes[16] == 4;
    if (!ok_sizes){ k_sentinel<<<12, 256, 0, stream>>>(out, 600000.0f); return; }

    const size_t OFF_XA   = 256;        // fp32 x (written by layer 3 only)
    const size_t OFF_TMPR = 25600256;   // CSR temp region (dead after build)
    const size_t OFF_BA   = 51200256;   // xb A (fp8)
    const size_t OFF_IPTR = 64262400;
    const size_t OFF_ESRC = 64662464;
    const size_t OFF_WF   = 67863296;
    const size_t OFF_WCF  = 68387584;
    const size_t OFF_BB_B = 68526848;   // xb B (fp8)
    const size_t REQ      = 81326848;
    if (ws_size < REQ){ k_sentinel<<<12, 256, 0, stream>>>(out, 500000.0f); return; }

    const size_t OFF_TMP2 = OFF_TMPR;
    const size_t OFF_CNT  = OFF_TMPR + 3200000;
    const size_t OFF_SOFF = OFF_TMPR + 3401216;
    const size_t OFF_TOT  = OFF_TMPR + 3602176;
    const size_t OFF_BBB  = OFF_TMPR + 3603200;

    char* ws = (char*)d_ws;
    float*    xA   = (float*)(ws + OFF_XA);
    unsigned* bA   = (unsigned*)(ws + OFF_BA);
    unsigned* bB   = (unsigned*)(ws + OFF_BB_B);
    int*      iptr = (int*)(ws + OFF_IPTR);
    int*      esrc = (int*)(ws + OFF_ESRC);
    uint4*    wf   = (uint4*)(ws + OFF_WF);
    uint4*    wcf  = (uint4*)(ws + OFF_WCF);
    unsigned* tmp  = (unsigned*)(ws + OFF_TMP2);
    int*      cnt  = (int*)(ws + OFF_CNT);
    int*      soff = (int*)(ws + OFF_SOFF);
    int*      tot  = (int*)(ws + OFF_TOT);
    int*      bb   = (int*)(ws + OFF_BBB);

    // K1: weight splits + edge histogram (independent, merged)
    k_pre<<<336, 256, 0, stream>>>(Wc, wcf, gW1, gW2, wf, eidx, cnt);
    // K2: initial embedding (needs wcf) + bucket totals (needs cnt)
    k_embed_btot<<<978, 256, 0, stream>>>(z, pos, emb, Wp, bp, bc, wcf, bA, cnt, tot);
    // K3: scan-of-totals (inline) + per-bucket scatter offsets
    k_soff2<<<NBK, 256, 0, stream>>>(cnt, tot, soff, bb);
    k_part <<<256, 256, 0, stream>>>(eidx, cnt, soff, tmp);
    k_final<<<NBK, 256, 0, stream>>>(bb, tmp, esrc, iptr);

    // fused GIN layers on fp8 buffers: bA->bB->bA->bB, layer 3 emits fp32 xA
    unsigned* bi = bA;  unsigned* bo = bB;
    for (int l=0;l<4;l++){
        int wx  = (l == 3) ? 1 : 0;
        int wxb = (l <  3) ? 1 : 0;
        k_gin_fused<<<(NN+31)/32, 256, 0, stream>>>(bi, iptr, esrc,
            gb1 + (size_t)l*H, gb2 + (size_t)l*H, wf, xA, bo, l, (l<3)?1:0, wx, wxb);
        unsigned* bt = bi; bi = bo; bo = bt;
    }

    // K6: pool + heads + evidential epilogue, fused per graph
    k_phe<<<NG, 256, 0, stream>>>(xA, batch, hW1, hb1, hW2, hb2, out);
}

// Round 8
// 300.225 us; speedup vs baseline: 1.1624x; 1.1624x over previous
//
#include <hip/hip_runtime.h>
#include <stdint.h>

#define NN 50000
#define NE 800000
#define NG 512
#define H  128
#define NBK 196      // ceil(NN/256) node buckets
#define EPB 3125     // edges per partition block (NE/256)

typedef __attribute__((ext_vector_type(8))) short short8;
typedef __attribute__((ext_vector_type(16))) float f32x16;
typedef __attribute__((ext_vector_type(2))) float float2v;

union U4S8 { uint4 u; short8 s; };

__device__ __forceinline__ float softplusf(float x){
    return fmaxf(x, 0.f) + log1pf(expf(-fabsf(x)));
}

__device__ __forceinline__ unsigned rne_bf16_hi(float x){
    unsigned u = __float_as_uint(x);
    unsigned r = u + 0x7fffu + ((u >> 16) & 1u);
    return r & 0xffff0000u;
}

__device__ __forceinline__ void split_pack(float x0, float x1, unsigned &hi, unsigned &lo){
    unsigned h0 = rne_bf16_hi(x0), h1 = rne_bf16_hi(x1);
    hi = (h0 >> 16) | h1;
    float l0 = x0 - __uint_as_float(h0);
    float l1 = x1 - __uint_as_float(h1);
    unsigned g0 = rne_bf16_hi(l0), g1 = rne_bf16_hi(l1);
    lo = (g0 >> 16) | g1;
}

// ---------------- sentinel writer ----------------
__global__ void k_sentinel(float* out, float val){
    int i = blockIdx.x*256 + threadIdx.x;
    if (i < 6*NG) out[i] = val;
}

// ================ K1: merged {W_comb split | GIN W split | edge hist} ================
__global__ __launch_bounds__(256) void k_pre(
    const float* __restrict__ Wc, uint4* __restrict__ wcf,
    const float* __restrict__ gW1, const float* __restrict__ gW2, uint4* __restrict__ wf,
    const int* __restrict__ ei, int* __restrict__ cnt)
{
    __shared__ int hist[256];
    const int bx = blockIdx.x, t = threadIdx.x;
    if (bx < 16){
        int bid = bx*4 + (t >> 6), lane = t & 63;
        int ntg = bid >> 4, ks = bid & 15;
        int n  = ntg*32 + (lane & 31);
        int kb = ks*16 + (lane >> 5)*8;
        unsigned hi[4], lo[4];
#pragma unroll
        for (int d=0; d<4; d++){
            float x0 = Wc[(size_t)(kb + 2*d    )*H + n];
            float x1 = Wc[(size_t)(kb + 2*d + 1)*H + n];
            split_pack(x0, x1, hi[d], lo[d]);
        }
        wcf[((0*4 + ntg)*16 + ks)*64 + lane] = make_uint4(hi[0],hi[1],hi[2],hi[3]);
        wcf[((1*4 + ntg)*16 + ks)*64 + lane] = make_uint4(lo[0],lo[1],lo[2],lo[3]);
    } else if (bx < 80){
        int bid = (bx-16)*4 + (t >> 6), lane = t & 63;
        int mat = bid >> 5, ntg = (bid >> 3) & 3, ks = bid & 7;
        int l = mat >> 1;
        const float* W = (mat & 1) ? (gW2 + (size_t)l*H*H) : (gW1 + (size_t)l*H*H);
        int n  = ntg*32 + (lane & 31);
        int kb = ks*16 + (lane >> 5)*8;
        unsigned hi[4], lo[4];
#pragma unroll
        for (int d=0; d<4; d++){
            float x0 = W[(size_t)(kb + 2*d    )*H + n];
            float x1 = W[(size_t)(kb + 2*d + 1)*H + n];
            split_pack(x0, x1, hi[d], lo[d]);
        }
        int bh = ((mat*2 + 0)*4 + ntg)*8 + ks;
        int bl = ((mat*2 + 1)*4 + ntg)*8 + ks;
        wf[bh*64 + lane] = make_uint4(hi[0],hi[1],hi[2],hi[3]);
        wf[bl*64 + lane] = make_uint4(lo[0],lo[1],lo[2],lo[3]);
    } else {
        int blk = bx - 80;
        hist[t] = 0;
        __syncthreads();
        int e0 = blk*EPB, e1 = min(e0+EPB, NE);
        for (int e = e0+t; e < e1; e += 256){
            int d = ei[NE+e];
            if ((unsigned)d < NN) atomicAdd(&hist[d>>8], 1);
        }
        __syncthreads();
        if (t < NBK) cnt[t*256 + blk] = hist[t];
    }
}

// ================ K2: merged {initial embedding MFMA | bucket totals} ================
// blocks 0..781 : embed role (writes fp8 xb);  blocks 782..977 : btot role
__global__ __launch_bounds__(256) void k_embed_btot(const int* __restrict__ z,
    const float* __restrict__ pos, const float* __restrict__ emb,
    const float* __restrict__ Wp, const float* __restrict__ bp,
    const float* __restrict__ bc, const uint4* __restrict__ wcf,
    unsigned* __restrict__ xbu,
    const int* __restrict__ cnt, int* __restrict__ tot)
{
    __shared__ unsigned short AhiF[2*8*64*8];
    __shared__ unsigned short AloF[2*8*64*8];
    const int t = threadIdx.x;
    if (blockIdx.x >= 782){
        int* s = (int*)AhiF;
        int k = blockIdx.x - 782;
        s[t] = cnt[k*256 + t];
        __syncthreads();
        for (int sd=128; sd>0; sd>>=1){
            if (t < sd) s[t] += s[t+sd];
            __syncthreads();
        }
        if (t == 0) tot[k] = s[0];
        return;
    }
    const int lane = t & 63, w = t >> 6;
    const int rt = w & 1, cp = w >> 1;
    const int mb = blockIdx.x * 64;
    const int c31 = lane & 31;
    const int q = lane >> 5;

    const int r = t >> 2, c4 = t & 3;
    const int gr = mb + r;
    const int gre = (gr < NN) ? gr : (NN-1);
    const int zr = z[gre];
    const float p0 = pos[gre*3+0], p1 = pos[gre*3+1], p2 = pos[gre*3+2];
    const int rt_s = r >> 5, r31s = r & 31;

    f32x16 acc0, acc1;
#pragma unroll
    for (int i=0;i<16;i++){ acc0[i]=0.f; acc1[i]=0.f; }

#pragma unroll
    for (int kh2=0; kh2<2; kh2++){
        if (kh2) __syncthreads();
#pragma unroll
        for (int i=0;i<8;i++){
            int cl = c4*4 + i*16;
            float4 v;
            if (kh2 == 0){
                v = *(const float4*)(emb + (size_t)zr*H + cl);
            } else {
                float4 w0 = *(const float4*)(Wp + cl);
                float4 w1 = *(const float4*)(Wp + H + cl);
                float4 w2 = *(const float4*)(Wp + 2*H + cl);
                float4 bb = *(const float4*)(bp + cl);
                v.x = p0*w0.x + p1*w1.x + p2*w2.x + bb.x;
                v.y = p0*w0.y + p1*w1.y + p2*w2.y + bb.y;
                v.z = p0*w0.z + p1*w1.z + p2*w2.z + bb.z;
                v.w = p0*w0.w + p1*w1.w + p2*w2.w + bb.w;
            }
            unsigned h0,l0,h1,l1;
            split_pack(v.x, v.y, h0, l0);
            split_pack(v.z, v.w, h1, l1);
            int idx = ((rt_s*8 + (cl>>4))*64 + ((cl>>3)&1)*32 + r31s)*8 + (cl & 7);
            *(uint2*)&AhiF[idx] = make_uint2(h0, h1);
            *(uint2*)&AloF[idx] = make_uint2(l0, l1);
        }
        __syncthreads();
#pragma unroll
        for (int ks=0; ks<8; ks++){
            int ksg = kh2*8 + ks;
            U4S8 ah, al, bh0, bl0, bh1, bl1;
            ah.u  = *(const uint4*)&AhiF[((rt*8+ks)*64 + lane)*8];
            al.u  = *(const uint4*)&AloF[((rt*8+ks)*64 + lane)*8];
            bh0.u = wcf[((0*4 + 2*cp+0)*16 + ksg)*64 + lane];
            bl0.u = wcf[((1*4 + 2*cp+0)*16 + ksg)*64 + lane];
            bh1.u = wcf[((0*4 + 2*cp+1)*16 + ksg)*64 + lane];
            bl1.u = wcf[((1*4 + 2*cp+1)*16 + ksg)*64 + lane];
            acc0 = __builtin_amdgcn_mfma_f32_32x32x16_bf16(ah.s, bh0.s, acc0, 0,0,0);
            acc0 = __builtin_amdgcn_mfma_f32_32x32x16_bf16(ah.s, bl0.s, acc0, 0,0,0);
            acc0 = __builtin_amdgcn_mfma_f32_32x32x16_bf16(al.s, bh0.s, acc0, 0,0,0);
            acc1 = __builtin_amdgcn_mfma_f32_32x32x16_bf16(ah.s, bh1.s, acc1, 0,0,0);
            acc1 = __builtin_amdgcn_mfma_f32_32x32x16_bf16(ah.s, bl1.s, acc1, 0,0,0);
            acc1 = __builtin_amdgcn_mfma_f32_32x32x16_bf16(al.s, bh1.s, acc1, 0,0,0);
        }
    }

    const float bva = bc[64*cp + c31], bvb = bc[64*cp + 32 + c31];
#pragma unroll
    for (int reg=0; reg<16; reg++){
        int row = 32*rt + (reg & 3) + 8*(reg >> 2) + 4*q;
        int mm = mb + row;
        if (mm < NN){
            float v0 = fmaxf(acc0[reg] + bva, 0.f);   // col 64cp + c31
            float v1 = fmaxf(acc1[reg] + bvb, 0.f);   // col 64cp + 32 + c31
            float pa = __shfl_xor(v0, 1);
            float pb = __shfl_xor(v1, 1);
            unsigned q0 = (unsigned)__builtin_amdgcn_cvt_pk_fp8_f32(v0, pa, 0, false) & 0xffffu;
            unsigned q1 = (unsigned)__builtin_amdgcn_cvt_pk_fp8_f32(v1, pb, 0, false) & 0xffffu;
            unsigned r0 = (unsigned)__shfl_xor((int)q0, 2);
            unsigned r1 = (unsigned)__shfl_xor((int)q1, 2);
            if (!(lane & 3)){
                xbu[(size_t)mm*32 + 16*cp      + (c31>>2)] = q0 | (r0 << 16);
                xbu[(size_t)mm*32 + 16*cp + 8  + (c31>>2)] = q1 | (r1 << 16);
            }
        }
    }
}

// ================ K3: soff with inline scan-of-totals ================
__global__ __launch_bounds__(256) void k_soff2(const int* __restrict__ cnt,
    const int* __restrict__ tot, int* __restrict__ soff, int* __restrict__ bb)
{
    __shared__ int P[256], sc[256];
    int k = blockIdx.x, t = threadIdx.x;
    int tv = (t < NBK) ? tot[t] : 0;
    P[t] = tv;
    for (int off=1; off<256; off<<=1){
        __syncthreads();
        int a = (t >= off) ? P[t-off] : 0;
        __syncthreads();
        P[t] += a;
    }
    __syncthreads();
    int bbk = (k == 0) ? 0 : P[k-1];
    if (k == 0){
        if (t == 0) bb[0] = 0;
        if (t < NBK) bb[t+1] = P[t];
    }
    int v = cnt[k*256 + t];
    sc[t] = v;
    for (int off=1; off<256; off<<=1){
        __syncthreads();
        int a = (t >= off) ? sc[t-off] : 0;
        __syncthreads();
        sc[t] += a;
    }
    __syncthreads();
    soff[k*256 + t] = bbk + sc[t] - v;
}

// ---------------- FUSED GIN layer v6 (REVERTED from v7): fp8 gather, quarter-wave/row ----------------
// v7 (16 acc regs, 1 pass) regressed: VGPR 92, occ 16%, 50.1us.  v6 is the verified best.
__global__ __launch_bounds__(256) void k_gin_fused(
    const unsigned* __restrict__ xbin,
    const int* __restrict__ iptr, const int* __restrict__ esrc,
    const float* __restrict__ b1, const float* __restrict__ b2,
    const uint4* __restrict__ wf,
    float* __restrict__ xout, unsigned* __restrict__ xbout,
    int l, int relu2, int wx, int wxb)
{
    __shared__ unsigned short AhiF[8*64*8];   // 8 KB
    __shared__ unsigned short AloF[8*64*8];   // 8 KB
    __shared__ int eS[1024];                  // 4 KB staged edge indices
    const int t = threadIdx.x, lane = t & 63, w = t >> 6;
    const int mb = blockIdx.x * 32;
    const int c31 = lane & 31;
    const int q = lane >> 5;
    const int c  = lane & 15;       // col chunk (8 cols = 8 B fp8)
    const int jr = lane >> 4;       // row-within-pass (0..3)
    const int ksw = c >> 1, qw = c & 1;

    const uint2* __restrict__ xbp = (const uint2*)xbin;   // row stride 16 uint2 (128 B)

    // ---- stage this block's contiguous edge-index range into LDS ----
    const int eTop = (mb + 32 < NN) ? (mb + 32) : NN;
    int e0b = iptr[mb];
    int e1b = iptr[eTop];
    e0b = max(0, min(e0b, NE));
    e1b = max(e0b, min(e1b, NE));
    const int ecnt = e1b - e0b;
    for (int i = t; i < ecnt && i < 1024; i += 256) eS[i] = esrc[e0b + i];
    __syncthreads();
    const int eCap = e0b + 1024;

#define ACC8(U)  { float2v _f; \
    _f = __builtin_amdgcn_cvt_pk_f32_fp8((int)(U).x, false); a0 += _f.x; a1 += _f.y; \
    _f = __builtin_amdgcn_cvt_pk_f32_fp8((int)(U).x, true ); a2 += _f.x; a3 += _f.y; \
    _f = __builtin_amdgcn_cvt_pk_f32_fp8((int)(U).y, false); a4 += _f.x; a5 += _f.y; \
    _f = __builtin_amdgcn_cvt_pk_f32_fp8((int)(U).y, true ); a6 += _f.x; a7 += _f.y; }

#define GLOOP(IX) { \
    for (; j+8 <= e; j += 8){ \
        int i0=IX(j+0), i1=IX(j+1), i2=IX(j+2), i3=IX(j+3); \
        int i4=IX(j+4), i5=IX(j+5), i6=IX(j+6), i7=IX(j+7); \
        uint2 u0 = xbp[(unsigned)i0*16u + c]; \
        uint2 u1 = xbp[(unsigned)i1*16u + c]; \
        uint2 u2 = xbp[(unsigned)i2*16u + c]; \
        uint2 u3 = xbp[(unsigned)i3*16u + c]; \
        uint2 u4 = xbp[(unsigned)i4*16u + c]; \
        uint2 u5 = xbp[(unsigned)i5*16u + c]; \
        uint2 u6 = xbp[(unsigned)i6*16u + c]; \
        uint2 u7 = xbp[(unsigned)i7*16u + c]; \
        ACC8(u0); ACC8(u1); ACC8(u2); ACC8(u3); \
        ACC8(u4); ACC8(u5); ACC8(u6); ACC8(u7); \
    } \
    for (; j+2 <= e; j += 2){ \
        int i0=IX(j+0), i1=IX(j+1); \
        uint2 u0 = xbp[(unsigned)i0*16u + c]; \
        uint2 u1 = xbp[(unsigned)i1*16u + c]; \
        ACC8(u0); ACC8(u1); \
    } \
    if (j < e){ \
        int i0=IX(j); \
        uint2 u0 = xbp[(unsigned)i0*16u + c]; \
        ACC8(u0); \
    } }

#define EIX_L(J) eS[(J) - e0b]
#define EIX_G(J) esrc[(J)]

#pragma unroll
    for (int p=0; p<2; p++){
        int m  = w*8 + p*4 + jr;
        int mm = mb + m;
        int mme = (mm < NN) ? mm : (NN-1);
        int s = iptr[mme], e = iptr[mme+1];
        s = max(0, min(s, NE));
        e = max(s, min(e, NE));
        // self term from fp8 xb
        float a0=0.f,a1=0.f,a2=0.f,a3=0.f,a4=0.f,a5=0.f,a6=0.f,a7=0.f;
        {
            uint2 su = xbp[(size_t)mme*16 + c];
            ACC8(su);
        }
        int j = s;
        if (s >= e0b && e <= eCap){
            GLOOP(EIX_L);
        } else {
            GLOOP(EIX_G);
        }
        unsigned hi4x, hi4y, hi4z, hi4w, lo4x, lo4y, lo4z, lo4w;
        split_pack(a0, a1, hi4x, lo4x);
        split_pack(a2, a3, hi4y, lo4y);
        split_pack(a4, a5, hi4z, lo4z);
        split_pack(a6, a7, hi4w, lo4w);
        int idx = (ksw*64 + qw*32 + (m ^ ksw))*8;
        *(uint4*)&AhiF[idx] = make_uint4(hi4x, hi4y, hi4z, hi4w);
        *(uint4*)&AloF[idx] = make_uint4(lo4x, lo4y, lo4z, lo4w);
    }
#undef EIX_G
#undef EIX_L
#undef GLOOP
#undef ACC8
    __syncthreads();

    const float bv1 = b1[w*32 + c31];
    const float bv2 = b2[w*32 + c31];
    const int mat1 = l*2, mat2 = l*2 + 1;

    f32x16 acc;
#pragma unroll
    for (int i=0;i<16;i++) acc[i] = 0.f;

    // ---- phase 1: T = relu(h@W1 + b1) ----
#pragma unroll
    for (int ks=0; ks<8; ks++){
        U4S8 ah, al, bh, bl;
        ah.u = *(const uint4*)&AhiF[(ks*64 + q*32 + (c31 ^ ks))*8];
        al.u = *(const uint4*)&AloF[(ks*64 + q*32 + (c31 ^ ks))*8];
        bh.u = wf[(((mat1*2+0)*4 + w)*8 + ks)*64 + lane];
        bl.u = wf[(((mat1*2+1)*4 + w)*8 + ks)*64 + lane];
        acc = __builtin_amdgcn_mfma_f32_32x32x16_bf16(ah.s, bh.s, acc, 0,0,0);
        acc = __builtin_amdgcn_mfma_f32_32x32x16_bf16(ah.s, bl.s, acc, 0,0,0);
        acc = __builtin_amdgcn_mfma_f32_32x32x16_bf16(al.s, bh.s, acc, 0,0,0);
    }

    // ---- T -> LDS frag-order (bf16 hi/lo), swizzled ----
    __syncthreads();
    {
        int k   = w*32 + c31;
        int kst = k >> 4, qt = (k >> 3) & 1, jj = k & 7;
#pragma unroll
        for (int reg=0; reg<16; reg++){
            int row = (reg & 3) + 8*(reg >> 2) + 4*q;
            float v = fmaxf(acc[reg] + bv1, 0.f);
            int idx = (kst*64 + qt*32 + (row ^ kst))*8 + jj;
            unsigned hb = rne_bf16_hi(v);
            AhiF[idx] = (unsigned short)(hb >> 16);
            AloF[idx] = (unsigned short)(rne_bf16_hi(v - __uint_as_float(hb)) >> 16);
        }
    }
    __syncthreads();

    // ---- phase 2: Y = T@W2 + b2 ----
#pragma unroll
    for (int i=0;i<16;i++) acc[i] = 0.f;
#pragma unroll
    for (int ks=0; ks<8; ks++){
        U4S8 ah, al, bh, bl;
        ah.u = *(const uint4*)&AhiF[(ks*64 + q*32 + (c31 ^ ks))*8];
        al.u = *(const uint4*)&AloF[(ks*64 + q*32 + (c31 ^ ks))*8];
        bh.u = wf[(((mat2*2+0)*4 + w)*8 + ks)*64 + lane];
        bl.u = wf[(((mat2*2+1)*4 + w)*8 + ks)*64 + lane];
        acc = __builtin_amdgcn_mfma_f32_32x32x16_bf16(ah.s, bh.s, acc, 0,0,0);
        acc = __builtin_amdgcn_mfma_f32_32x32x16_bf16(ah.s, bl.s, acc, 0,0,0);
        acc = __builtin_amdgcn_mfma_f32_32x32x16_bf16(al.s, bh.s, acc, 0,0,0);
    }

    // ---- epilogue: conditional fp32 / fp8 outputs ----
#pragma unroll
    for (int reg=0; reg<16; reg++){
        int row = (reg & 3) + 8*(reg >> 2) + 4*q;
        int mm = mb + row;
        if (mm < NN){
            float v = acc[reg] + bv2;     // col w*32 + c31
            if (relu2) v = fmaxf(v, 0.f);
            if (wx) xout[(size_t)mm*H + w*32 + c31] = v;
            if (wxb){
                float p1 = __shfl_xor(v, 1);
                unsigned qq = (unsigned)__builtin_amdgcn_cvt_pk_fp8_f32(v, p1, 0, false) & 0xffffu;
                unsigned rr = (unsigned)__shfl_xor((int)qq, 2);
                if (!(lane & 3)){
                    xbout[(size_t)mm*32 + w*8 + (c31>>2)] = qq | (rr << 16);
                }
            }
        }
    }
}

// ================ CSR partition kernels ================
// k_part v2.1: histogram from cnt[] (computed in k_pre) — guarded for t >= NBK
__global__ __launch_bounds__(256) void k_part(const int* __restrict__ ei,
    const int* __restrict__ cnt, const int* __restrict__ soff, unsigned* __restrict__ tmp)
{
    __shared__ unsigned edgeL[EPB];
    __shared__ int sc[256], startv[256], curv[256];
    __shared__ int tots;
    int blk = blockIdx.x, t = threadIdx.x;
    int v = (t < NBK) ? cnt[t*256 + blk] : 0;
    sc[t] = v;
    for (int off=1; off<256; off<<=1){
        __syncthreads();
        int tv = (t >= off) ? sc[t-off] : 0;
        __syncthreads();
        sc[t] += tv;
    }
    __syncthreads();
    startv[t] = sc[t] - v;
    curv[t]   = sc[t] - v;
    if (t == 255) tots = sc[255];
    __syncthreads();
    int e0 = blk*EPB, e1 = min(e0+EPB, NE);
    for (int e = e0+t; e < e1; e += 256){
        int d = ei[NE+e];
        if ((unsigned)d < NN){
            unsigned u = (unsigned)ei[e] | ((unsigned)d << 16);
            int p = atomicAdd(&curv[d>>8], 1);
            edgeL[p] = u;
        }
    }
    __syncthreads();
    int nTot = tots;
    for (int i = t; i < nTot; i += 256){
        unsigned u = edgeL[i];
        int b = u >> 24;
        int g = soff[b*256 + blk] + (i - startv[b]);
        tmp[g] = u;
    }
}

__global__ __launch_bounds__(256) void k_final(const int* __restrict__ bb,
    const unsigned* __restrict__ tmp, int* __restrict__ esrc, int* __restrict__ iptr)
{
    __shared__ int cntN[256], sc[256], curN[256];
    int k = blockIdx.x, t = threadIdx.x;
    int n0 = k*256;
    int nn = min(256, NN - n0);
    int base = bb[k], end = bb[k+1];
    cntN[t] = 0;
    __syncthreads();
    for (int i = base+t; i < end; i += 256){
        int d = (int)(tmp[i] >> 16) - n0;
        if ((unsigned)d < 256u) atomicAdd(&cntN[d], 1);
    }
    __syncthreads();
    int v = cntN[t];
    sc[t] = v;
    for (int off=1; off<256; off<<=1){
        __syncthreads();
        int tv = (t >= off) ? sc[t-off] : 0;
        __syncthreads();
        sc[t] += tv;
    }
    __syncthreads();
    int excl = sc[t] - v;
    curN[t] = excl;
    if (t < nn) iptr[n0 + t] = base + excl;
    if (k == NBK-1 && t == 0) iptr[NN] = end;
    __syncthreads();
    for (int i = base+t; i < end; i += 256){
        unsigned u = tmp[i];
        int d = (int)(u >> 16) - n0;
        if ((unsigned)d < 256u){
            int p = atomicAdd(&curN[d], 1);
            esrc[base + p] = (int)(u & 0xffffu);
        }
    }
}

// ================ K6: fused pool + 4 heads + evidential epilogue (per graph) ================
__global__ __launch_bounds__(256) void k_phe(const float* __restrict__ x,
    const int* __restrict__ batch,
    const float* __restrict__ W1, const float* __restrict__ b1,
    const float* __restrict__ W2, const float* __restrict__ b2,
    float* __restrict__ out)
{
    __shared__ float aggL[128];
    __shared__ float redL[256];
    __shared__ float okL[4];
    int g = blockIdx.x, t = threadIdx.x;
    int c = t & 127, half = t >> 7;
    int lo=0, hi=NN;
    while (lo<hi){ int mid=(lo+hi)>>1; if (batch[mid] < g) lo=mid+1; else hi=mid; }
    int s0 = lo;
    hi = NN;
    while (lo<hi){ int mid=(lo+hi)>>1; if (batch[mid] < g+1) lo=mid+1; else hi=mid; }
    int e0 = lo;
    int n  = e0 - s0;
    int sh = s0 + (half ? (n>>1) : 0);
    int eh = half ? e0 : (s0 + (n>>1));
    float a0=0.f, a1=0.f, a2=0.f, a3=0.f;
    int i = sh;
    for (; i+4 <= eh; i += 4){
        a0 += x[(size_t)(i+0)*H + c];
        a1 += x[(size_t)(i+1)*H + c];
        a2 += x[(size_t)(i+2)*H + c];
        a3 += x[(size_t)(i+3)*H + c];
    }
    for (; i < eh; i++) a0 += x[(size_t)i*H + c];
    float v = (a0+a1) + (a2+a3);
    if (half) redL[c] = v;
    __syncthreads();
    if (!half) aggL[c] = v + redL[c];
    __syncthreads();
    for (int kk = half; kk < 4; kk += 2){
        float acc = b1[kk*H + c];
        const float* wp = W1 + (size_t)kk*H*H + c;
#pragma unroll 8
        for (int qq=0; qq<H; qq++) acc += aggL[qq] * wp[(size_t)qq*H];
        redL[half*128 + c] = fmaxf(acc, 0.f) * W2[kk*H + c];
        __syncthreads();
        for (int sd=64; sd>0; sd>>=1){
            if (c < sd) redL[half*128 + c] += redL[half*128 + c + sd];
            __syncthreads();
        }
        if (c == 0) okL[kk] = redL[half*128];
        __syncthreads();
    }
    if (t == 0){
        float o0 = okL[0] + b2[0];
        float o1 = okL[1] + b2[1];
        float o2 = okL[2] + b2[2];
        float o3 = okL[3] + b2[3];
        float alpha = fmaxf(softplusf(o0) + 1.f, 1.f + 1e-4f);
        float beta  = softplusf(o1);
        float nu    = softplusf(o2);
        float am1   = alpha - 1.f;
        out[0*NG+g] = o3;
        out[1*NG+g] = beta / am1;
        out[2*NG+g] = beta / (am1 * nu);
        out[3*NG+g] = nu;
        out[4*NG+g] = alpha;
        out[5*NG+g] = beta;
    }
}

extern "C" void kernel_launch(void* const* d_in, const int* in_sizes, int n_in,
                              void* d_out, int out_size, void* d_ws, size_t ws_size,
                              hipStream_t stream)
{
    const int*   z     = (const int*)d_in[0];
    const float* pos   = (const float*)d_in[1];
    const int*   batch = (const int*)d_in[2];
    const int*   eidx  = (const int*)d_in[3];
    const float* emb   = (const float*)d_in[4];
    const float* Wp    = (const float*)d_in[5];
    const float* bp    = (const float*)d_in[6];
    const float* Wc    = (const float*)d_in[7];
    const float* bc    = (const float*)d_in[8];
    const float* gW1   = (const float*)d_in[9];
    const float* gb1   = (const float*)d_in[10];
    const float* gW2   = (const float*)d_in[11];
    const float* gb2   = (const float*)d_in[12];
    const float* hW1   = (const float*)d_in[13];
    const float* hb1   = (const float*)d_in[14];
    const float* hW2   = (const float*)d_in[15];
    const float* hb2   = (const float*)d_in[16];
    float* out = (float*)d_out;

    bool ok_sizes = (n_in == 17)
        && in_sizes[0] == NN && in_sizes[1] == NN*3 && in_sizes[2] == NN
        && in_sizes[3] == 2*NE && in_sizes[4] == 100*H
        && in_sizes[7] == 2*H*H && in_sizes[9] == 4*H*H
        && in_sizes[13] == 4*H*H && in_sizes[16] == 4;
    if (!ok_sizes){ k_sentinel<<<12, 256, 0, stream>>>(out, 600000.0f); return; }

    const size_t OFF_XA   = 256;        // fp32 x (written by layer 3 only)
    const size_t OFF_TMPR = 25600256;   // CSR temp region (dead after build)
    const size_t OFF_BA   = 51200256;   // xb A (fp8)
    const size_t OFF_IPTR = 64262400;
    const size_t OFF_ESRC = 64662464;
    const size_t OFF_WF   = 67863296;
    const size_t OFF_WCF  = 68387584;
    const size_t OFF_BB_B = 68526848;   // xb B (fp8)
    const size_t REQ      = 81326848;
    if (ws_size < REQ){ k_sentinel<<<12, 256, 0, stream>>>(out, 500000.0f); return; }

    const size_t OFF_TMP2 = OFF_TMPR;
    const size_t OFF_CNT  = OFF_TMPR + 3200000;
    const size_t OFF_SOFF = OFF_TMPR + 3401216;
    const size_t OFF_TOT  = OFF_TMPR + 3602176;
    const size_t OFF_BBB  = OFF_TMPR + 3603200;

    char* ws = (char*)d_ws;
    float*    xA   = (float*)(ws + OFF_XA);
    unsigned* bA   = (unsigned*)(ws + OFF_BA);
    unsigned* bB   = (unsigned*)(ws + OFF_BB_B);
    int*      iptr = (int*)(ws + OFF_IPTR);
    int*      esrc = (int*)(ws + OFF_ESRC);
    uint4*    wf   = (uint4*)(ws + OFF_WF);
    uint4*    wcf  = (uint4*)(ws + OFF_WCF);
    unsigned* tmp  = (unsigned*)(ws + OFF_TMP2);
    int*      cnt  = (int*)(ws + OFF_CNT);
    int*      soff = (int*)(ws + OFF_SOFF);
    int*      tot  = (int*)(ws + OFF_TOT);
    int*      bb   = (int*)(ws + OFF_BBB);

    // K1: weight splits + edge histogram (independent, merged)
    k_pre<<<336, 256, 0, stream>>>(Wc, wcf, gW1, gW2, wf, eidx, cnt);
    // K2: initial embedding (needs wcf) + bucket totals (needs cnt)
    k_embed_btot<<<978, 256, 0, stream>>>(z, pos, emb, Wp, bp, bc, wcf, bA, cnt, tot);
    // K3: scan-of-totals (inline) + per-bucket scatter offsets
    k_soff2<<<NBK, 256, 0, stream>>>(cnt, tot, soff, bb);
    k_part <<<256, 256, 0, stream>>>(eidx, cnt, soff, tmp);
    k_final<<<NBK, 256, 0, stream>>>(bb, tmp, esrc, iptr);

    // fused GIN layers on fp8 buffers: bA->bB->bA->bB, layer 3 emits fp32 xA
    unsigned* bi = bA;  unsigned* bo = bB;
    for (int l=0;l<4;l++){
        int wx  = (l == 3) ? 1 : 0;
        int wxb = (l <  3) ? 1 : 0;
        k_gin_fused<<<(NN+31)/32, 256, 0, stream>>>(bi, iptr, esrc,
            gb1 + (size_t)l*H, gb2 + (size_t)l*H, wf, xA, bo, l, (l<3)?1:0, wx, wxb);
        unsigned* bt = bi; bi = bo; bo = bt;
    }

    // K6: pool + heads + evidential epilogue, fused per graph
    k_phe<<<NG, 256, 0, stream>>>(xA, batch, hW1, hb1, hW2, hb2, out);
}